// Round 1
// baseline (27.975 us; speedup 1.0000x reference)
//
#include <hip/hip_runtime.h>
#include <hip/hip_bf16.h>
#include <math.h>

// Problem constants (from reference): B=4, C=256, W=H=256, n=256
#define BDIM 4
#define CDIM 256
#define WH   65536
#define NIDX 256

__inline__ __device__ float wave_reduce_sum(float v) {
    // full 64-lane butterfly
    #pragma unroll
    for (int off = 32; off > 0; off >>= 1)
        v += __shfl_down(v, off, 64);
    return v;
}

// One block per (b, j) pair. 256 threads, thread c handles channel c.
__global__ __launch_bounds__(256) void cossim_pairs_kernel(
        const float* __restrict__ x1, const float* __restrict__ x2,
        const int* __restrict__ i1, const int* __restrict__ i2,
        float* __restrict__ partial) {
    const int blk = blockIdx.x;       // 0 .. B*n-1
    const int b   = blk >> 8;         // / NIDX
    const int j   = blk & (NIDX - 1);
    const int c   = threadIdx.x;

    const int idx1 = i1[j];
    const int idx2 = i2[j];

    const size_t base = ((size_t)b * CDIM + c) * (size_t)WH;

    // 4 scattered loads per thread; issue all before use (ILP)
    const float a1 = x1[base + (size_t)idx1];
    const float b1 = x1[base + (size_t)idx2];
    const float a2 = x2[base + (size_t)idx1];
    const float b2 = x2[base + (size_t)idx2];

    float s[6];
    s[0] = a1 * b1;   // dot1
    s[1] = a1 * a1;   // |a1|^2
    s[2] = b1 * b1;   // |b1|^2
    s[3] = a2 * b2;   // dot2
    s[4] = a2 * a2;   // |a2|^2
    s[5] = b2 * b2;   // |b2|^2

    // wave-level reduce each of the 6 sums, then cross-wave via LDS
    __shared__ float sm[4][6];
    const int lane = c & 63;
    const int wid  = c >> 6;   // 0..3
    #pragma unroll
    for (int k = 0; k < 6; ++k) {
        float r = wave_reduce_sum(s[k]);
        if (lane == 0) sm[wid][k] = r;
    }
    __syncthreads();

    if (c == 0) {
        float t[6];
        #pragma unroll
        for (int k = 0; k < 6; ++k)
            t[k] = sm[0][k] + sm[1][k] + sm[2][k] + sm[3][k];
        const float denom1 = fmaxf(sqrtf(t[1]) * sqrtf(t[2]), 1e-8f);
        const float denom2 = fmaxf(sqrtf(t[4]) * sqrtf(t[5]), 1e-8f);
        const float D1 = t[0] / denom1;
        const float D2 = t[3] / denom2;
        partial[blk] = fabsf(D1 - D2);
    }
}

// Single-block final mean over B*n = 1024 partials.
__global__ __launch_bounds__(256) void final_mean_kernel(
        const float* __restrict__ partial, float* __restrict__ out) {
    const int t = threadIdx.x;  // 256 threads
    float v = partial[t] + partial[t + 256] + partial[t + 512] + partial[t + 768];
    v = wave_reduce_sum(v);
    __shared__ float sm[4];
    if ((t & 63) == 0) sm[t >> 6] = v;
    __syncthreads();
    if (t == 0)
        out[0] = (sm[0] + sm[1] + sm[2] + sm[3]) * (1.0f / (float)(BDIM * NIDX));
}

extern "C" void kernel_launch(void* const* d_in, const int* in_sizes, int n_in,
                              void* d_out, int out_size, void* d_ws, size_t ws_size,
                              hipStream_t stream) {
    const float* x1 = (const float*)d_in[0];
    const float* x2 = (const float*)d_in[1];
    const int*   i1 = (const int*)d_in[2];
    const int*   i2 = (const int*)d_in[3];
    float* out = (float*)d_out;
    float* partial = (float*)d_ws;   // needs B*n*4 = 4 KB

    const int nblocks = BDIM * NIDX;  // 1024
    cossim_pairs_kernel<<<nblocks, 256, 0, stream>>>(x1, x2, i1, i2, partial);
    final_mean_kernel<<<1, 256, 0, stream>>>(partial, out);
}